// Round 1
// baseline (238.755 us; speedup 1.0000x reference)
//
#include <hip/hip_runtime.h>

// PoolingNms: 3 chained pool/unpool passes (k=3,5,6) on 16x1x1080x1920 fp32.
// 1080 and 1920 divide by 3,5,6 -> no crop/pad ever. lcm(3,5,6)=30, so every
// 30x30 tile is independent across all three stages. Fuse everything in one
// kernel: LDS tile of 30x240 (8 supertiles wide), in-place window NMS.

#define IMG_H 1080
#define IMG_W 1920
#define TILE_H 30
#define TILE_W 240
#define NTHREADS 256

// One stage: KxK non-overlapping windows over the 30x240 LDS tile.
// Each window handled by exactly one thread (disjoint -> in-place safe).
// Strict '>' scan in row-major (r*K+c) order == jnp.argmax first-occurrence.
template <int K>
__device__ __forceinline__ void nms_stage(float (*tile)[TILE_W], int t) {
    constexpr int NWR = TILE_H / K;
    constexpr int NWC = TILE_W / K;
    for (int w = t; w < NWR * NWC; w += NTHREADS) {
        const int wr = w / NWC;
        const int wc = w - wr * NWC;
        const int r0 = wr * K;
        const int c0 = wc * K;
        float mx = -1.0f;  // inputs are >= 0
        int am = 0;
#pragma unroll
        for (int r = 0; r < K; ++r)
#pragma unroll
            for (int c = 0; c < K; ++c) {
                const float v = tile[r0 + r][c0 + c];
                if (v > mx) { mx = v; am = r * K + c; }
            }
#pragma unroll
        for (int r = 0; r < K; ++r)
#pragma unroll
            for (int c = 0; c < K; ++c)
                tile[r0 + r][c0 + c] = (r * K + c == am) ? mx : 0.0f;
    }
    __syncthreads();
}

__global__ __launch_bounds__(NTHREADS) void pooling_nms_kernel(
    const float* __restrict__ x, float* __restrict__ out) {
    __shared__ float tile[TILE_H][TILE_W];

    const int t = threadIdx.x;
    const int col0 = blockIdx.x * TILE_W;
    const int row0 = blockIdx.y * TILE_H;
    const size_t base = (size_t)blockIdx.z * (IMG_H * (size_t)IMG_W) +
                        (size_t)row0 * IMG_W + col0;
    const float* src = x + base;
    float* dst = out + base;

    // Coalesced float4 load: 30*240/4 = 1800 vec4 per block, 60 per row.
    constexpr int VPR = TILE_W / 4;  // 60
    constexpr int NV = TILE_H * VPR; // 1800
    for (int i = t; i < NV; i += NTHREADS) {
        const int r = i / VPR;
        const int c4 = i - r * VPR;
        const float4 v =
            *reinterpret_cast<const float4*>(src + (size_t)r * IMG_W + c4 * 4);
        *reinterpret_cast<float4*>(&tile[r][c4 * 4]) = v;
    }
    __syncthreads();

    nms_stage<3>(tile, t);  // 10x80 = 800 windows
    nms_stage<5>(tile, t);  //  6x48 = 288 windows
    nms_stage<6>(tile, t);  //  5x40 = 200 windows

    // Coalesced float4 store.
    for (int i = t; i < NV; i += NTHREADS) {
        const int r = i / VPR;
        const int c4 = i - r * VPR;
        *reinterpret_cast<float4*>(dst + (size_t)r * IMG_W + c4 * 4) =
            *reinterpret_cast<const float4*>(&tile[r][c4 * 4]);
    }
}

extern "C" void kernel_launch(void* const* d_in, const int* in_sizes, int n_in,
                              void* d_out, int out_size, void* d_ws, size_t ws_size,
                              hipStream_t stream) {
    const float* x = (const float*)d_in[0];
    float* out = (float*)d_out;
    dim3 grid(IMG_W / TILE_W, IMG_H / TILE_H, 16);  // 8 x 36 x 16 = 4608 blocks
    pooling_nms_kernel<<<grid, NTHREADS, 0, stream>>>(x, out);
}